// Round 2
// baseline (5617.197 us; speedup 1.0000x reference)
//
#include <hip/hip_runtime.h>
#include <hip/hip_bf16.h>
#include <math.h>

// Problem constants
// B=32, T=64, V=32000, E=256, H=512, 4H=2048, Krec=1024, Mlog=2016

typedef __attribute__((ext_vector_type(8))) short short8;
typedef __attribute__((ext_vector_type(4))) float floatx4;

#define MFMA16(a, b, c) __builtin_amdgcn_mfma_f32_16x16x32_bf16((a), (b), (c), 0, 0, 0)

__device__ __forceinline__ unsigned short f2bf(float f) {
  unsigned u = __builtin_bit_cast(unsigned, f);
  return (unsigned short)((u + 0x7fffu + ((u >> 16) & 1u)) >> 16);
}

__device__ __forceinline__ float sigm(float x) { return 1.f / (1.f + expf(-x)); }

// ---------------------------------------------------------------------------
// Prep: combined recurrent weights, gate-permuted (j' = u*4 + g), layout [j'][k]
// RS[j'*1024+k] = k<512 ? WihS[j][k] (u_prev part) : WhhS[j][k-512],  j = g*512+u
// ---------------------------------------------------------------------------
__global__ void k_prep_rec(const float* __restrict__ WihS, const float* __restrict__ WhhS,
                           const float* __restrict__ WihU, const float* __restrict__ WhhU,
                           float* __restrict__ RS, float* __restrict__ RU) {
  const int n = 2048 * 1024;
  for (int i = blockIdx.x * blockDim.x + threadIdx.x; i < n; i += gridDim.x * blockDim.x) {
    int k = i & 1023;
    int jp = i >> 10;
    int u = jp >> 2, g = jp & 3;
    int j = g * 512 + u;
    RS[i] = (k < 512) ? WihS[j * 768 + k] : WhhS[j * 512 + (k - 512)];
    RU[i] = (k < 512) ? WihU[j * 768 + k] : WhhU[j * 512 + (k - 512)];
  }
}

// e-part weights, bf16, layout [j'][k] (k = 0..255 over E), + permuted bias sums
__global__ void k_prep_e(const float* __restrict__ WihS, const float* __restrict__ WihU,
                         const float* __restrict__ bihS, const float* __restrict__ bhhS,
                         const float* __restrict__ bihU, const float* __restrict__ bhhU,
                         unsigned short* __restrict__ ESb, unsigned short* __restrict__ EUb,
                         float* __restrict__ biasS, float* __restrict__ biasU) {
  const int n = 2048 * 256;
  for (int i = blockIdx.x * blockDim.x + threadIdx.x; i < n; i += gridDim.x * blockDim.x) {
    int k = i & 255;
    int jp = i >> 8;
    int j = (jp & 3) * 512 + (jp >> 2);
    ESb[i] = f2bf(WihS[j * 768 + 512 + k]);
    EUb[i] = f2bf(WihU[j * 768 + 512 + k]);
    if (i < 2048) {
      int jb = (i & 3) * 512 + (i >> 2);
      biasS[i] = bihS[jb] + bhhS[jb];
      biasU[i] = bihU[jb] + bhhU[jb];
    }
  }
}

__global__ void k_cast_fcw(const float* __restrict__ w, unsigned short* __restrict__ o) {
  const int n4 = 32000 * 512 / 4;
  const float4* w4 = (const float4*)w;
  ushort4* o4 = (ushort4*)o;
  for (int i = blockIdx.x * blockDim.x + threadIdx.x; i < n4; i += gridDim.x * blockDim.x) {
    float4 v = w4[i];
    ushort4 r;
    r.x = f2bf(v.x); r.y = f2bf(v.y); r.z = f2bf(v.z); r.w = f2bf(v.w);
    o4[i] = r;
  }
}

// hS0 = features @ sz_w.T + sz_b ; zero-init hU0, cS, cU
__global__ void k_init(const float* __restrict__ features, const float* __restrict__ sz_w,
                       const float* __restrict__ sz_b, float* __restrict__ hS0,
                       float* __restrict__ hU0, float* __restrict__ cS, float* __restrict__ cU) {
  int g = blockIdx.x * blockDim.x + threadIdx.x;  // 16384 = 32*512
  int b = g >> 9, u = g & 511;
  const float4* fr = (const float4*)(features + b * 256);
  const float4* wr = (const float4*)(sz_w + u * 256);
  float acc = sz_b[u];
  #pragma unroll 8
  for (int k = 0; k < 64; ++k) {
    float4 f = fr[k], w = wr[k];
    acc += f.x * w.x + f.y * w.y + f.z * w.z + f.w * w.w;
  }
  hS0[b * 512 + u] = acc;
  hU0[b * 512 + u] = 0.f;
  cS[b * 512 + u] = 0.f;
  cU[b * 512 + u] = 0.f;
}

// ---------------------------------------------------------------------------
// P[t][b][j'] = e(t,b) @ Eb[j']^T + bias[j']   (bf16 MFMA, f32 out)
// rows rr = t*32+b, 32 rows/block (same t), 64 cols/block; grid (32, 64)
// ---------------------------------------------------------------------------
__global__ __launch_bounds__(256) void k_embed_P(const int* __restrict__ captions,
                                                 const float* __restrict__ embed,
                                                 const unsigned short* __restrict__ Eb,
                                                 const float* __restrict__ biasp,
                                                 float* __restrict__ P) {
  __shared__ unsigned short sh[32][264];  // +8 pad: breaks 512B-stride bank conflict
  const int ct = blockIdx.x, rt = blockIdx.y;
  const int tid = threadIdx.x;
  {
    int row = tid >> 3, seg = tid & 7;
    int rr = rt * 32 + row;
    int t = rr >> 5, b = rr & 31;
    int idx = (t == 0) ? 0 : captions[b * 64 + (t - 1)];
    const float4* ep = (const float4*)(embed + idx * 256) + seg * 8;
    #pragma unroll
    for (int k = 0; k < 8; ++k) {
      float4 v = ep[k];
      int base = seg * 32 + k * 4;
      sh[row][base + 0] = f2bf(v.x);
      sh[row][base + 1] = f2bf(v.y);
      sh[row][base + 2] = f2bf(v.z);
      sh[row][base + 3] = f2bf(v.w);
    }
  }
  __syncthreads();
  const int w = tid >> 6, l = tid & 63;
  const int lr = l & 15, lk = (l >> 4) * 8, lrow4 = (l >> 4) * 4;
  const int n16 = ct * 64 + w * 16;
  floatx4 acc0 = {0.f, 0.f, 0.f, 0.f}, acc1 = {0.f, 0.f, 0.f, 0.f};
  #pragma unroll
  for (int kt = 0; kt < 8; ++kt) {
    short8 a0 = *(const short8*)&sh[lr][kt * 32 + lk];
    short8 a1 = *(const short8*)&sh[16 + lr][kt * 32 + lk];
    short8 bf = *(const short8*)(Eb + (n16 + lr) * 256 + kt * 32 + lk);
    acc0 = MFMA16(a0, bf, acc0);
    acc1 = MFMA16(a1, bf, acc1);
  }
  float bias = biasp[n16 + lr];
  #pragma unroll
  for (int r = 0; r < 4; ++r) {
    int row0 = rt * 32 + lrow4 + r;
    P[row0 * 2048 + n16 + lr] = acc0[r] + bias;
    P[(row0 + 16) * 2048 + n16 + lr] = acc1[r] + bias;
  }
}

// ---------------------------------------------------------------------------
// One LSTM substep: gates = P[t] + [xA|xB] @ R ; fused activation.
// 256 blocks x 256 thr; block owns 8 gate-cols (2 units, all 4 gates in-wave).
// thread = (b = tid>>3, jj = tid&7); K=1024 f32 dot.
// ---------------------------------------------------------------------------
__global__ __launch_bounds__(256) void k_step(const float* __restrict__ Pt,
                                              const float* __restrict__ xA,
                                              const float* __restrict__ xB,
                                              const float* __restrict__ R,
                                              float* __restrict__ c, float* __restrict__ hout,
                                              unsigned short* __restrict__ hrec) {
  const int tid = threadIdx.x;
  const int b = tid >> 3, jj = tid & 7;
  const int jp = blockIdx.x * 8 + jj;
  const float4* xa = (const float4*)(xA + b * 512);
  const float4* xb = (const float4*)(xB + b * 512);
  const float4* wa = (const float4*)(R + jp * 1024);
  const float4* wb = wa + 128;
  float a0 = 0.f, a1 = 0.f, a2 = 0.f, a3 = 0.f;
  #pragma unroll 8
  for (int k = 0; k < 128; k += 4) {
    float4 x0 = xa[k],     w0 = wa[k];
    float4 x1 = xa[k + 1], w1 = wa[k + 1];
    float4 x2 = xa[k + 2], w2 = wa[k + 2];
    float4 x3 = xa[k + 3], w3 = wa[k + 3];
    a0 += x0.x * w0.x + x0.y * w0.y + x0.z * w0.z + x0.w * w0.w;
    a1 += x1.x * w1.x + x1.y * w1.y + x1.z * w1.z + x1.w * w1.w;
    a2 += x2.x * w2.x + x2.y * w2.y + x2.z * w2.z + x2.w * w2.w;
    a3 += x3.x * w3.x + x3.y * w3.y + x3.z * w3.z + x3.w * w3.w;
  }
  #pragma unroll 8
  for (int k = 0; k < 128; k += 4) {
    float4 x0 = xb[k],     w0 = wb[k];
    float4 x1 = xb[k + 1], w1 = wb[k + 1];
    float4 x2 = xb[k + 2], w2 = wb[k + 2];
    float4 x3 = xb[k + 3], w3 = wb[k + 3];
    a0 += x0.x * w0.x + x0.y * w0.y + x0.z * w0.z + x0.w * w0.w;
    a1 += x1.x * w1.x + x1.y * w1.y + x1.z * w1.z + x1.w * w1.w;
    a2 += x2.x * w2.x + x2.y * w2.y + x2.z * w2.z + x2.w * w2.w;
    a3 += x3.x * w3.x + x3.y * w3.y + x3.z * w3.z + x3.w * w3.w;
  }
  float acc = Pt[b * 2048 + jp] + ((a0 + a1) + (a2 + a3));
  const int l = tid & 63;
  const int gb = l & ~3;  // 4-lane gate group (i,f,g,o)
  float iv = __shfl(acc, gb + 0, 64);
  float fv = __shfl(acc, gb + 1, 64);
  float gv = __shfl(acc, gb + 2, 64);
  float ov = __shfl(acc, gb + 3, 64);
  if ((jj & 3) == 0) {
    int u = jp >> 2;
    int ci = b * 512 + u;
    float cn = sigm(fv) * c[ci] + sigm(iv) * tanhf(gv);
    float hn = sigm(ov) * tanhf(cn);
    c[ci] = cn;
    hout[ci] = hn;
    if (hrec) hrec[ci] = f2bf(hn);
  }
}

// ---------------------------------------------------------------------------
// logits[b][t][v] = hS[t][b][:] . fcw[v][:] + fcb[v]   (bf16 MFMA)
// A rows rA = t*32+b (M=2016), N=32000, K=512. 250 blocks, M-loop inside
// so fc_w is read exactly once per block (B is the big operand).
// ---------------------------------------------------------------------------
__global__ __launch_bounds__(256) void k_logits(const unsigned short* __restrict__ hS,
                                                const unsigned short* __restrict__ fcw,
                                                const float* __restrict__ fcb,
                                                float* __restrict__ out) {
  const int w = threadIdx.x >> 6, l = threadIdx.x & 63;
  const int lr = l & 15, lk = (l >> 4) * 8, lrow4 = (l >> 4) * 4;
  const int n0 = blockIdx.x * 128 + w * 32;  // wave's 32-col slice
  const float bb0 = fcb[n0 + lr];
  const float bb1 = fcb[n0 + 16 + lr];
  for (int mt = 0; mt < 63; ++mt) {
    floatx4 acc00 = {0.f, 0.f, 0.f, 0.f}, acc01 = {0.f, 0.f, 0.f, 0.f};
    floatx4 acc10 = {0.f, 0.f, 0.f, 0.f}, acc11 = {0.f, 0.f, 0.f, 0.f};
    #pragma unroll 4
    for (int kt = 0; kt < 16; ++kt) {
      short8 a0 = *(const short8*)(hS + (mt * 32 + lr) * 512 + kt * 32 + lk);
      short8 a1 = *(const short8*)(hS + (mt * 32 + 16 + lr) * 512 + kt * 32 + lk);
      short8 b0 = *(const short8*)(fcw + (n0 + lr) * 512 + kt * 32 + lk);
      short8 b1 = *(const short8*)(fcw + (n0 + 16 + lr) * 512 + kt * 32 + lk);
      acc00 = MFMA16(a0, b0, acc00);
      acc01 = MFMA16(a0, b1, acc01);
      acc10 = MFMA16(a1, b0, acc10);
      acc11 = MFMA16(a1, b1, acc11);
    }
    #pragma unroll
    for (int r = 0; r < 4; ++r) {
      int rA0 = mt * 32 + lrow4 + r;
      int rA1 = rA0 + 16;
      int b0i = rA0 & 31, t0 = rA0 >> 5;
      int b1i = rA1 & 31, t1 = rA1 >> 5;
      out[(b0i * 63 + t0) * 32000 + n0 + lr]      = acc00[r] + bb0;
      out[(b0i * 63 + t0) * 32000 + n0 + 16 + lr] = acc01[r] + bb1;
      out[(b1i * 63 + t1) * 32000 + n0 + lr]      = acc10[r] + bb0;
      out[(b1i * 63 + t1) * 32000 + n0 + 16 + lr] = acc11[r] + bb1;
    }
  }
}

// ---------------------------------------------------------------------------
extern "C" void kernel_launch(void* const* d_in, const int* in_sizes, int n_in,
                              void* d_out, int out_size, void* d_ws, size_t ws_size,
                              hipStream_t stream) {
  const float* features = (const float*)d_in[0];
  const int* captions   = (const int*)d_in[1];
  const float* embed    = (const float*)d_in[2];
  const float* WihS = (const float*)d_in[3];
  const float* WhhS = (const float*)d_in[4];
  const float* bihS = (const float*)d_in[5];
  const float* bhhS = (const float*)d_in[6];
  const float* WihU = (const float*)d_in[7];
  const float* WhhU = (const float*)d_in[8];
  const float* bihU = (const float*)d_in[9];
  const float* bhhU = (const float*)d_in[10];
  const float* fc_w = (const float*)d_in[11];
  const float* fc_b = (const float*)d_in[12];
  const float* sz_w = (const float*)d_in[13];
  const float* sz_b = (const float*)d_in[14];

  // Scratch in d_out (dead before k_logits overwrites): PS, PU, RS, RU
  char* ob = (char*)d_out;
  float* PS = (float*)(ob + 0);          // 64*32*2048 f32 = 16 MiB
  float* PU = (float*)(ob + 16777216);   // 16 MiB
  float* RS = (float*)(ob + 33554432);   // 2048*1024 f32 = 8 MiB
  float* RU = (float*)(ob + 41943040);   // 8 MiB

  // Workspace layout (~35.7 MiB)
  char* ws = (char*)d_ws;
  unsigned short* ESb = (unsigned short*)(ws + 0);        // 2048*256 bf16
  unsigned short* EUb = (unsigned short*)(ws + 1048576);
  float* biasS = (float*)(ws + 2097152);                  // 2048 f32
  float* biasU = (float*)(ws + 2105344);
  float* HS0 = (float*)(ws + 2113536);                    // 32*512 f32 each
  float* HS1 = (float*)(ws + 2179072);
  float* HU0 = (float*)(ws + 2244608);
  float* HU1 = (float*)(ws + 2310144);
  float* CS  = (float*)(ws + 2375680);
  float* CU  = (float*)(ws + 2441216);
  unsigned short* HSA = (unsigned short*)(ws + 2506752);  // 64*32*512 bf16
  unsigned short* FCW = (unsigned short*)(ws + 4603904);  // 32000*512 bf16
  (void)in_sizes; (void)n_in; (void)out_size; (void)ws_size;

  k_prep_rec<<<2048, 256, 0, stream>>>(WihS, WhhS, WihU, WhhU, RS, RU);
  k_prep_e<<<1024, 256, 0, stream>>>(WihS, WihU, bihS, bhhS, bihU, bhhU, ESb, EUb, biasS, biasU);
  k_cast_fcw<<<2048, 256, 0, stream>>>(fc_w, FCW);
  k_init<<<64, 256, 0, stream>>>(features, sz_w, sz_b, HS0, HU0, CS, CU);
  k_embed_P<<<dim3(32, 64), 256, 0, stream>>>(captions, embed, ESb, biasS, PS);
  k_embed_P<<<dim3(32, 64), 256, 0, stream>>>(captions, embed, EUb, biasU, PU);

  for (int t = 0; t < 64; ++t) {
    float* hSp = (t & 1) ? HS1 : HS0;
    float* hSq = (t & 1) ? HS0 : HS1;
    float* hUp = (t & 1) ? HU1 : HU0;
    float* hUq = (t & 1) ? HU0 : HU1;
    // S-LSTM: x = [u_prev | hS_prev], writes hS_new (+bf16 record for logits)
    k_step<<<256, 256, 0, stream>>>(PS + t * 65536, hUp, hSp, RS, CS, hSq, HSA + t * 16384);
    // U-LSTM: x = [hS_new | hU_prev], writes hU_new
    k_step<<<256, 256, 0, stream>>>(PU + t * 65536, hSq, hUp, RU, CU, hUq, (unsigned short*)nullptr);
  }

  k_logits<<<250, 256, 0, stream>>>(HSA, FCW, fc_b, (float*)d_out);
}